// Round 1
// baseline (400.883 us; speedup 1.0000x reference)
//
#include <hip/hip_runtime.h>

// Problem constants (match reference)
constexpr int B = 4, L = 2048, C = 16, R = 16;
constexpr int M = R * R;       // 256 elements per matrix (1 KB)
constexpr int G = 64;          // chunks per chain
constexpr int S = L / G;       // 32 time steps per chunk
constexpr int T = 4;           // time steps per LDS tile (float4 load granularity)

// flat offset of element (b, l, c, 0, 0) in [B, L, C, R, R]
__device__ __forceinline__ long mat_off(int b, int l, int c) {
    return (((long)b * L + l) * C + c) * M;
}

// Pass 1: per-chunk aggregates.
//   Aagg = A_{t_end} ... A_{t_start}            (matrix product)
//   Xagg = local scan value at chunk end with zero entry state
// ws slot for chunk (bc, g): 512 floats = [Aagg(256) | Xagg(256)]
__global__ __launch_bounds__(256) void pass1_chunk_agg(
    const float* __restrict__ A, const float* __restrict__ X,
    float* __restrict__ ws) {
    const int blk = blockIdx.x;           // bc * G + g
    const int g   = blk % G;
    const int bc  = blk / G;
    const int b   = bc / C, c = bc % C;
    const int tid = threadIdx.x;
    const int i = tid >> 4, j = tid & 15;

    __shared__ float sA[T][M];
    __shared__ float sX[T][M];
    __shared__ float aggA[M];
    __shared__ float aggX[M];

    aggA[tid] = (i == j) ? 1.0f : 0.0f;
    aggX[tid] = 0.0f;

    const int tm = tid >> 6;              // which matrix of the tile (0..3)
    const int e4 = (tid & 63) << 2;       // float offset within matrix

    for (int t0 = 0; t0 < S; t0 += T) {
        const int l = g * S + t0 + tm;
        const float4 va = *(const float4*)(A + mat_off(b, l, c) + e4);
        const float4 vx = *(const float4*)(X + mat_off(b, l, c) + e4);
        // previous inner iteration ended with a barrier -> safe to overwrite tiles
        *(float4*)&sA[tm][e4] = va;
        *(float4*)&sX[tm][e4] = vx;
        __syncthreads();
        for (int s = 0; s < T; ++s) {
            float accA = 0.0f;
            float accX = sX[s][tid];
            #pragma unroll
            for (int k = 0; k < 16; ++k) {
                const float a = sA[s][(i << 4) + k];
                accA += a * aggA[(k << 4) + j];
                accX += a * aggX[(k << 4) + j];
            }
            __syncthreads();              // all reads of old agg done
            aggA[tid] = accA;
            aggX[tid] = accX;
            __syncthreads();              // new agg visible
        }
    }
    float* slot = ws + (long)blk * (2 * M);
    slot[tid]     = aggA[tid];            // own element -> no barrier needed
    slot[M + tid] = aggX[tid];
}

// Pass 2: sequential scan over the G chunk aggregates of one chain.
// Writes the EXCLUSIVE Y-carry for chunk g in-place over its Xagg slot.
__global__ __launch_bounds__(256) void pass2_scan(float* __restrict__ ws) {
    const int bc  = blockIdx.x;           // 0 .. B*C-1
    const int tid = threadIdx.x;
    const int i = tid >> 4, j = tid & 15;

    __shared__ float sAg[M];
    __shared__ float carry[M];
    carry[tid] = 0.0f;

    float* base = ws + (long)bc * G * (2 * M);
    for (int g = 0; g < G; ++g) {
        float* slot = base + (long)g * (2 * M);
        sAg[tid] = slot[tid];             // Aagg_g
        const float xg  = slot[M + tid];  // Xagg_g
        const float old = carry[tid];     // own element (exclusive carry)
        __syncthreads();                  // sAg visible; all carry writes from prev iter done
        float acc = xg;
        #pragma unroll
        for (int k = 0; k < 16; ++k)
            acc += sAg[(i << 4) + k] * carry[(k << 4) + j];
        slot[M + tid] = old;              // exclusive Y-carry out
        __syncthreads();                  // all reads of old carry done
        carry[tid] = acc;
        __syncthreads();
    }
}

// Pass 3: re-run the recurrence within each chunk starting from its carry.
__global__ __launch_bounds__(256) void pass3_apply(
    const float* __restrict__ A, const float* __restrict__ X,
    const float* __restrict__ ws, float* __restrict__ out) {
    const int blk = blockIdx.x;           // bc * G + g
    const int g   = blk % G;
    const int bc  = blk / G;
    const int b   = bc / C, c = bc % C;
    const int tid = threadIdx.x;
    const int i = tid >> 4, j = tid & 15;

    __shared__ float sA[T][M];
    __shared__ float sX[T][M];
    __shared__ float Y[M];

    Y[tid] = ws[(long)blk * (2 * M) + M + tid];   // exclusive Y-carry

    const int tm = tid >> 6;
    const int e4 = (tid & 63) << 2;

    for (int t0 = 0; t0 < S; t0 += T) {
        const int l = g * S + t0 + tm;
        const float4 va = *(const float4*)(A + mat_off(b, l, c) + e4);
        const float4 vx = *(const float4*)(X + mat_off(b, l, c) + e4);
        *(float4*)&sA[tm][e4] = va;
        *(float4*)&sX[tm][e4] = vx;
        __syncthreads();
        for (int s = 0; s < T; ++s) {
            float acc = sX[s][tid];
            #pragma unroll
            for (int k = 0; k < 16; ++k)
                acc += sA[s][(i << 4) + k] * Y[(k << 4) + j];
            __syncthreads();              // all reads of old Y done
            Y[tid] = acc;
            out[mat_off(b, g * S + t0 + s, c) + tid] = acc;   // coalesced 1 KB store
            __syncthreads();
        }
    }
}

extern "C" void kernel_launch(void* const* d_in, const int* in_sizes, int n_in,
                              void* d_out, int out_size, void* d_ws, size_t ws_size,
                              hipStream_t stream) {
    const float* A = (const float*)d_in[0];
    const float* X = (const float*)d_in[1];
    float* out = (float*)d_out;
    float* ws  = (float*)d_ws;   // needs B*C*G*512 floats = 8 MB

    pass1_chunk_agg<<<B * C * G, 256, 0, stream>>>(A, X, ws);
    pass2_scan<<<B * C, 256, 0, stream>>>(ws);
    pass3_apply<<<B * C * G, 256, 0, stream>>>(A, X, ws, out);
}